// Round 20
// baseline (568.028 us; speedup 1.0000x reference)
//
#include <hip/hip_runtime.h>
#include <hip/hip_bf16.h>
#include <stdint.h>

#define D_VIT 768
#define D_SAE 12288
#define TOPK 32
#define NC 32           // fast-path quorum: >=32 codes >= CQ(3.25)
#define CMAX 384        // candidate slots per row
#define THETA 3.1f      // encoder emission threshold (mfma-f32 domain)
#define SLOTS 24        // LDS staging slots per (row, block-col); overflow->fallback
#define NCF 48          // fallback superset size
#define CFB 512

typedef __attribute__((ext_vector_type(8))) short bf8_t;   // 8 bf16 (4 VGPRs)
typedef __attribute__((ext_vector_type(4))) float f4_t;    // 4 f32 acc
typedef __attribute__((ext_vector_type(4))) float f4v;
typedef const __attribute__((address_space(1))) void* gas_t;
typedef __attribute__((address_space(3))) void* las_t;

#define NTR_BLK 9216    // (D_SAE/32)*(D_VIT/32) transpose blocks
#define NCW_BLK 4608    // D_SAE*D_VIT/8/256 cvt_w blocks

// ---- fused: W_enc transpose (wt f32 + wtb bf16)  ||  wdecb = bf16(wdec) -----
__global__ __launch_bounds__(256) void k_prep_w(
    const float* __restrict__ wenc, float* __restrict__ wt,
    __hip_bfloat16* __restrict__ wtb, const float* __restrict__ wdec,
    __hip_bfloat16* __restrict__ wdecb) {
    int bid = blockIdx.x, tid = threadIdx.x;
    if (bid < NTR_BLK) {
        __shared__ float t[32][33];
        int f0 = (bid % 384) * 32, k0 = (bid / 384) * 32;
        int tx = tid & 31, ty = tid >> 5;
#pragma unroll
        for (int j = 0; j < 32; j += 8)
            t[ty + j][tx] = wenc[(size_t)(k0 + ty + j) * D_SAE + f0 + tx];
        __syncthreads();
#pragma unroll
        for (int j = 0; j < 32; j += 8) {
            float v = t[tx][ty + j];
            wt[(size_t)(f0 + ty + j) * D_VIT + k0 + tx] = v;
            wtb[(size_t)(f0 + ty + j) * D_VIT + k0 + tx] = __float2bfloat16(v);
        }
    } else {
        long long i = ((long long)(bid - NTR_BLK) * 256 + tid) * 8;
        float4 a = *reinterpret_cast<const float4*>(wdec + i);
        float4 b = *reinterpret_cast<const float4*>(wdec + i + 4);
        union { __hip_bfloat16 h[8]; uint4 v; } o;
        o.h[0] = __float2bfloat16(a.x); o.h[1] = __float2bfloat16(a.y);
        o.h[2] = __float2bfloat16(a.z); o.h[3] = __float2bfloat16(a.w);
        o.h[4] = __float2bfloat16(b.x); o.h[5] = __float2bfloat16(b.y);
        o.h[6] = __float2bfloat16(b.z); o.h[7] = __float2bfloat16(b.w);
        *reinterpret_cast<uint4*>(wdecb + i) = o.v;
    }
}

// ---- fused: xb = bf16(x - b_dec)  ||  zero cnt/fflag ------------------------
__global__ __launch_bounds__(256) void k_prep_x(
    const float* __restrict__ x, const float* __restrict__ bdec,
    __hip_bfloat16* __restrict__ xb, int* __restrict__ cnt,
    int* __restrict__ fflag, long long n, int nxblk, int M) {
    int bid = blockIdx.x, tid = threadIdx.x;
    if (bid < nxblk) {
        long long i = ((long long)bid * 256 + tid) * 8;
        if (i >= n) return;
        float4 a = *reinterpret_cast<const float4*>(x + i);
        float4 b = *reinterpret_cast<const float4*>(x + i + 4);
        int kk = (int)(i % D_VIT);
        float4 c = *reinterpret_cast<const float4*>(bdec + kk);
        float4 d = *reinterpret_cast<const float4*>(bdec + kk + 4);
        union { __hip_bfloat16 h[8]; uint4 v; } o;
        o.h[0] = __float2bfloat16(a.x - c.x); o.h[1] = __float2bfloat16(a.y - c.y);
        o.h[2] = __float2bfloat16(a.z - c.z); o.h[3] = __float2bfloat16(a.w - c.w);
        o.h[4] = __float2bfloat16(b.x - d.x); o.h[5] = __float2bfloat16(b.y - d.y);
        o.h[6] = __float2bfloat16(b.z - d.z); o.h[7] = __float2bfloat16(b.w - d.w);
        *reinterpret_cast<uint4*>(xb + i) = o.v;
    } else {
        int i = (bid - nxblk) * 256 + tid;
        if (i < M) { cnt[i] = 0; fflag[i] = 0; }
    }
}

// --- 128x128x64 4-wave dbuf MFMA encoder (64KB LDS -> 2 blocks/CU) -----------
#define GBM 128
#define GBN 128
#define GBK 64
#define NKT (D_VIT / GBK)   // 12

__global__ __launch_bounds__(256, 2) void k_enc8(
    const __hip_bfloat16* __restrict__ xb, const __hip_bfloat16* __restrict__ wtb,
    int* __restrict__ cnt, int* __restrict__ candb, int mrows) {
    __shared__ __hip_bfloat16 lds[2][2][GBM * GBK];   // 64 KiB (reused by epilogue)
    int tid = threadIdx.x;
    int lane = tid & 63, w = tid >> 6;
    int wm = w >> 1, wn = w & 1;                      // 2 x 2 waves
    int tile_m = blockIdx.y * GBM, tile_n = blockIdx.x * GBN;
    int lrow = lane & 15, lk = lane >> 4;

    f4_t acc[2][2][2][2] = {};                        // [MQ][f][NQ][g]

    // stage half h (0=A/xb, 1=B/wtb) of K-tile kt into buffer b: 4 loads.
    // 1024 granules of 16B; LDS linear dest, pre-swizzled global source
    // (rule #21): LDS (r, s) holds global granule s ^ (r&7).
    auto STAGE = [&](int kt, int h, int b) {
#pragma unroll
        for (int j = 0; j < 4; ++j) {
            int G = tid + j * 256;
            int r = G >> 3, s = G & 7;
            int gg = s ^ (r & 7);
            if (h == 0) {
                int ar = tile_m + r;
                if (ar >= mrows) ar = mrows - 1;
                const __hip_bfloat16* src = xb + (size_t)ar * D_VIT + kt * GBK + gg * 8;
                __builtin_amdgcn_global_load_lds((gas_t)src,
                    (las_t)(&lds[b][0][G * 8]), 16, 0, 0);
            } else {
                int br = tile_n + r;
                const __hip_bfloat16* src = wtb + (size_t)br * D_VIT + kt * GBK + gg * 8;
                __builtin_amdgcn_global_load_lds((gas_t)src,
                    (las_t)(&lds[b][1][G * 8]), 16, 0, 0);
            }
        }
    };

    // one quadrant phase: 8 ds_read_b128 + 8 MFMA (setprio-wrapped)
#define PHASE(MQ, NQ, BUF) do {                                                \
        const __hip_bfloat16* Ab = &lds[BUF][0][0];                            \
        const __hip_bfloat16* Bb = &lds[BUF][1][0];                            \
        bf8_t af[2][2], bv[2][2];                                              \
        _Pragma("unroll")                                                      \
        for (int f = 0; f < 2; ++f) {                                          \
            int ra = wm * 64 + (MQ) * 32 + f * 16 + lrow;                      \
            _Pragma("unroll")                                                  \
            for (int h = 0; h < 2; ++h) {                                      \
                int sl = (lk + 4 * h) ^ (ra & 7);                              \
                af[f][h] = *reinterpret_cast<const bf8_t*>(Ab + ra * GBK + sl * 8); \
            }                                                                  \
        }                                                                      \
        _Pragma("unroll")                                                      \
        for (int g = 0; g < 2; ++g) {                                          \
            int rb = wn * 64 + (NQ) * 32 + g * 16 + lrow;                      \
            _Pragma("unroll")                                                  \
            for (int h = 0; h < 2; ++h) {                                      \
                int sl = (lk + 4 * h) ^ (rb & 7);                              \
                bv[g][h] = *reinterpret_cast<const bf8_t*>(Bb + rb * GBK + sl * 8); \
            }                                                                  \
        }                                                                      \
        __builtin_amdgcn_s_setprio(1);                                         \
        _Pragma("unroll")                                                      \
        for (int h = 0; h < 2; ++h)                                            \
            _Pragma("unroll")                                                  \
            for (int f = 0; f < 2; ++f)                                        \
                _Pragma("unroll")                                              \
                for (int g = 0; g < 2; ++g)                                    \
                    acc[MQ][f][NQ][g] = __builtin_amdgcn_mfma_f32_16x16x32_bf16( \
                        bv[g][h], af[f][h], acc[MQ][f][NQ][g], 0, 0, 0);       \
        __builtin_amdgcn_s_setprio(0);                                         \
    } while (0)

    // prologue: stage K-tile 0 (8 loads in flight)
    STAGE(0, 0, 0);
    STAGE(0, 1, 0);

    int cur = 0;
#pragma unroll 1
    for (int t = 0; t < NKT; ++t) {
        int nb = cur ^ 1;
        bool pf = (t + 1 < NKT);
        if (pf) STAGE(t + 1, 0, nb);                 // A of t+1: 4 loads
        if (pf) asm volatile("s_waitcnt vmcnt(4)" ::: "memory");
        else    asm volatile("s_waitcnt vmcnt(0)" ::: "memory");
        __builtin_amdgcn_s_barrier();                // tile-t data visible to all
        asm volatile("" ::: "memory");
        __builtin_amdgcn_sched_barrier(0);
        PHASE(0, 0, cur);
        if (pf) STAGE(t + 1, 1, nb);                 // B of t+1: 4 loads
        PHASE(1, 0, cur);
        PHASE(0, 1, cur);
        PHASE(1, 1, cur);
        asm volatile("" ::: "memory");
        __builtin_amdgcn_s_barrier();                // all reads of buf[cur] done
        asm volatile("" ::: "memory");
        cur = nb;
    }
#undef PHASE

    // ---- epilogue: LDS-staged candidate emission (no global atomics in loop)
    __syncthreads();
    int* scnt  = reinterpret_cast<int*>(&lds[0][0][0]);   // [128]
    int* scand = scnt + 128;                              // [128][SLOTS]
    for (int r = tid; r < 128; r += 256) scnt[r] = 0;
    __syncthreads();

#pragma unroll
    for (int mq = 0; mq < 2; ++mq)
#pragma unroll
        for (int f = 0; f < 2; ++f) {
            int lr = wm * 64 + mq * 32 + f * 16 + lrow;
            int xr = tile_m + lr;
            if (xr < mrows) {
#pragma unroll
                for (int nq = 0; nq < 2; ++nq)
#pragma unroll
                    for (int g = 0; g < 2; ++g) {
                        int fb = tile_n + wn * 64 + nq * 32 + g * 16 + lk * 4;
#pragma unroll
                        for (int q = 0; q < 4; ++q) {
                            float r = acc[mq][f][nq][g][q];
                            if (r >= THETA) {
                                int slot = atomicAdd(&scnt[lr], 1);   // LDS atomic
                                if (slot < SLOTS) {
                                    union { __hip_bfloat16 h; unsigned short u; } cc;
                                    cc.h = __float2bfloat16(r);
                                    scand[lr * SLOTS + slot] =
                                        (int)(((unsigned)cc.u << 16) | (unsigned)(fb + q));
                                }
                            }
                        }
                    }
            }
        }
    __syncthreads();

    // flush: one global atomic per (row, block) — 128 in parallel
    if (tid < 128) {
        int xr = tile_m + tid;
        if (xr < mrows) {
            int c = scnt[tid];
            if (c > SLOTS) {
                atomicAdd(&cnt[xr], CMAX + 1);     // poison -> fallback (sum-deterministic)
            } else if (c > 0) {
                int base = atomicAdd(&cnt[xr], c);
                for (int i = 0; i < c; ++i) {
                    int g = base + i;
                    if (g < CMAX) candb[(size_t)xr * CMAX + g] = scand[tid * SLOTS + i];
                }
            }
        }
    }
}

// -------- per-row select: hist-vb -> band f64 rerank -> compact route --------
__global__ __launch_bounds__(256) void k_select(
    const int* __restrict__ cnt, const int* __restrict__ candb,
    const float* __restrict__ x, const float* __restrict__ bdec,
    const float* __restrict__ wt, const __hip_bfloat16* __restrict__ wdecb,
    float* __restrict__ out, int* __restrict__ fflag) {
    int row = blockIdx.x, tid = threadIdx.x;

    __shared__ float xs[D_VIT];
    __shared__ int cand[CMAX];
    __shared__ unsigned int hist[256];
    __shared__ float cvfin[CMAX];
    __shared__ float cexact[CMAX];
    __shared__ unsigned char cflag[CMAX];
    __shared__ short alist[CMAX];
    __shared__ short clist[TOPK];
    __shared__ float sval[TOPK];
    __shared__ int sidx[TOPK];
    __shared__ int s_nq, s_na, s_nd, s_nc, s_vbc;

    hist[tid] = 0;
    for (int c = tid; c < CMAX; c += 256) cflag[c] = 0;
    if (tid < TOPK) { sval[tid] = 0.f; sidx[tid] = 0; }
    if (tid == 0) { s_nq = 0; s_na = 0; s_nd = 0; s_nc = 0; s_vbc = 255; }
    if (tid < 192) {
        const float* xp = x + (size_t)row * D_VIT + tid * 4;
        float4 xv = *reinterpret_cast<const float4*>(xp);
        float4 bv = *reinterpret_cast<const float4*>(bdec + tid * 4);
        xs[tid * 4 + 0] = xv.x - bv.x; xs[tid * 4 + 1] = xv.y - bv.y;
        xs[tid * 4 + 2] = xv.z - bv.z; xs[tid * 4 + 3] = xv.w - bv.w;
    }
    int C0 = cnt[row];
    int C = C0 < CMAX ? C0 : CMAX;

    // load candidates + quorum + code histogram in one pass.
    // codes are >= bf16(3.09375)=0x4046, so bin = code-0x4040 in [6,255].
    unsigned CQ;
    { union { __hip_bfloat16 h; unsigned short u; } t2; t2.h = __float2bfloat16(3.25f); CQ = t2.u; }
    int nql = 0;
    for (int c = tid; c < C; c += 256) {
        int pk = candb[(size_t)row * CMAX + c];
        cand[c] = pk;
        unsigned code = (unsigned)pk >> 16;
        if (code >= CQ) nql++;
        int bin = (int)code - 0x4040;
        if (bin < 0) bin = 0; if (bin > 255) bin = 255;
        atomicAdd(&hist[bin], 1u);
    }
    if (nql) atomicAdd(&s_nq, nql);
    __syncthreads();

    // quorum: >=NC codes >= bf16(3.25). Exclusion proof: 32nd exact >=
    // 3.25-0.016-0.019 = 3.215 > excluded exact < 3.1+0.035 = 3.135.
    if (C0 > CMAX || s_nq < NC) {
        if (tid == 0) fflag[row] = 1;
        return;
    }

    // vb = 32nd-largest CODE via suffix scan over the 256-bin histogram (exact)
    if (tid < 64) {
        int l = tid;
        unsigned c0 = hist[4 * l], c1 = hist[4 * l + 1],
                 c2 = hist[4 * l + 2], c3 = hist[4 * l + 3];
        unsigned S = c0 + c1 + c2 + c3;
#pragma unroll
        for (int o = 1; o < 64; o <<= 1) {
            unsigned t = __shfl_down(S, o);
            if (l + o < 64) S += t;
        }
        unsigned above = __shfl_down(S, 1);
        if (l == 63) above = 0;
        if (S >= TOPK && above < TOPK) {       // crossing 4-bin group
            unsigned run = above;
            int bs = 4 * l;
            if (run + c3 >= TOPK)                 bs = 4 * l + 3;
            else if (run + c3 + c2 >= TOPK)       bs = 4 * l + 2;
            else if (run + c3 + c2 + c1 >= TOPK)  bs = 4 * l + 1;
            s_vbc = bs;
        }
    }
    __syncthreads();
    int vbc = s_vbc;
    if (vbc >= 255) {                      // degenerate tail -> exact fallback
        if (tid == 0) fflag[row] = 1;
        return;
    }
    float vb = __uint_as_float((unsigned)(0x4040 + vbc) << 16);

    // partition: definite-in / ambiguous band / excluded
    {
        float band = 0.025f + 0.018f * vb;
        for (int c = tid; c < C; c += 256) {
            float v = __uint_as_float(((unsigned)cand[c] >> 16) << 16);
            if (v > vb + band) { cflag[c] = 2; cvfin[c] = v; atomicAdd(&s_nd, 1); }
            else if (v >= vb - band) { int a = atomicAdd(&s_na, 1); alist[a] = (short)c; cflag[c] = 1; }
        }
    }
    __syncthreads();
    int na = s_na, nd = s_nd;

    // f64 rerank of band: 16 threads/cand -> 16 cands/pass (na~22 -> 2 passes)
    for (int base = 0; base < na; base += 16) {
        int ai = base + (tid >> 4), sub = tid & 15;
        if (ai < na) {
            int c = alist[ai];
            int f = (int)(((unsigned)cand[c]) & 0xffffu);
            const float* wr = wt + (size_t)f * D_VIT;
            double acc = 0.0;
#pragma unroll
            for (int i = 0; i < 12; ++i) {
                int k = sub * 4 + i * 64;
                float4 wv = *reinterpret_cast<const float4*>(wr + k);
                float4 xv = *reinterpret_cast<const float4*>(xs + k);
                acc += (double)wv.x * xv.x + (double)wv.y * xv.y
                     + (double)wv.z * xv.z + (double)wv.w * xv.w;
            }
            acc += __shfl_xor(acc, 1);  acc += __shfl_xor(acc, 2);
            acc += __shfl_xor(acc, 4);  acc += __shfl_xor(acc, 8);
            if (sub == 0) cexact[c] = (float)(acc > 0.0 ? acc : 0.0);
        }
    }
    __syncthreads();

    // choose top (32-nd) of the band by exact value (na x na, small)
    {
        int kq = TOPK - nd;
        for (int a = tid; a < na; a += 256) {
            int c = alist[a];
            float ex = cexact[c]; int mi = (int)(((unsigned)cand[c]) & 0xffffu);
            int rA = 0;
            for (int j = 0; j < na; ++j) {
                int cj = alist[j];
                float ej = cexact[cj]; int ij = (int)(((unsigned)cand[cj]) & 0xffffu);
                rA += (ej > ex) || (ej == ex && ij < mi);
            }
            if (rA < kq) { cflag[c] = 3; cvfin[c] = ex; }
        }
    }
    __syncthreads();

    // compact chosen (exactly 32) then content-rank 32 over 32
    for (int c = tid; c < C; c += 256) if (cflag[c] >= 2) {
        int a = atomicAdd(&s_nc, 1);
        if (a < TOPK) clist[a] = (short)c;
    }
    __syncthreads();
    if (tid < TOPK && tid < s_nc) {
        int c = clist[tid];
        float mv = cvfin[c]; int mi = (int)(((unsigned)cand[c]) & 0xffffu);
        int rk = 0;
        for (int j = 0; j < TOPK && j < s_nc; ++j) {
            int cj = clist[j];
            float vj = cvfin[cj]; int ij = (int)(((unsigned)cand[cj]) & 0xffffu);
            rk += (vj > mv) || (vj == mv && ij < mi);
        }
        if (rk < TOPK) { sval[rk] = mv; sidx[rk] = mi; }
    }
    __syncthreads();

    // decode: 8-wide explicit prefetch (4 serial round-trips instead of 32)
    if (tid < 192) {
        int d0 = tid * 4;
        float4 o = *reinterpret_cast<const float4*>(bdec + d0);
#pragma unroll
        for (int g = 0; g < 4; ++g) {
            uint2 u[8];
#pragma unroll
            for (int j = 0; j < 8; ++j)
                u[j] = *reinterpret_cast<const uint2*>(
                    wdecb + (size_t)sidx[g * 8 + j] * D_VIT + d0);
#pragma unroll
            for (int j = 0; j < 8; ++j) {
                float s = sval[g * 8 + j];
                o.x = fmaf(s, __uint_as_float(u[j].x << 16), o.x);
                o.y = fmaf(s, __uint_as_float(u[j].x & 0xffff0000u), o.y);
                o.z = fmaf(s, __uint_as_float(u[j].y << 16), o.z);
                o.w = fmaf(s, __uint_as_float(u[j].y & 0xffff0000u), o.w);
            }
        }
        f4v ov; ov.x = o.x; ov.y = o.y; ov.z = o.z; ov.w = o.w;
        __builtin_nontemporal_store(ov,
            reinterpret_cast<f4v*>(out + (size_t)row * D_VIT + d0));
    }
}

// -------- fallback: coalesced full f32 recompute, any-distribution exact -----
__global__ __launch_bounds__(256) void k_fallback(
    const int* __restrict__ fflag, const float* __restrict__ x,
    const float* __restrict__ bdec, const float* __restrict__ wt,
    const __hip_bfloat16* __restrict__ wdecb, float* __restrict__ out) {
    int row = blockIdx.x;
    if (fflag[row] == 0) return;
    int tid = threadIdx.x;

    __shared__ float xs[D_VIT];
    __shared__ unsigned short actl[D_SAE];
    __shared__ unsigned int hist1[256];
    __shared__ unsigned int hist2[128];
    __shared__ int cand[CFB];
    __shared__ double cval[CFB];
    __shared__ float sval[TOPK];
    __shared__ int sidx[TOPK];
    __shared__ int s_cnt, s_b1, s_code;
    __shared__ unsigned int s_above;

    hist1[tid] = 0;
    if (tid < 128) hist2[tid] = 0;
    if (tid < TOPK) { sval[tid] = 0.f; sidx[tid] = 0; }
    if (tid == 0) { s_cnt = 0; s_b1 = -1; s_code = 1; s_above = 0; }
    if (tid < 192) {
        float4 xv = *reinterpret_cast<const float4*>(x + (size_t)row * D_VIT + tid * 4);
        float4 bv = *reinterpret_cast<const float4*>(bdec + tid * 4);
        xs[tid * 4 + 0] = xv.x - bv.x; xs[tid * 4 + 1] = xv.y - bv.y;
        xs[tid * 4 + 2] = xv.z - bv.z; xs[tid * 4 + 3] = xv.w - bv.w;
    }
    __syncthreads();

    int fg = tid >> 2, sub = tid & 3;
    for (int pass = 0; pass < D_SAE / 64; ++pass) {
        int f = pass * 64 + fg;
        const float* wr = wt + (size_t)f * D_VIT;
        float a = 0.f;
        for (int j = 0; j < 48; ++j) {
            int k = sub * 4 + j * 16;
            float4 wv = *reinterpret_cast<const float4*>(wr + k);
            float4 xv = *reinterpret_cast<const float4*>(xs + k);
            a = fmaf(wv.x, xv.x, a); a = fmaf(wv.y, xv.y, a);
            a = fmaf(wv.z, xv.z, a); a = fmaf(wv.w, xv.w, a);
        }
        a += __shfl_xor(a, 1); a += __shfl_xor(a, 2);
        if (sub == 0) {
            union { __hip_bfloat16 h; unsigned short u; } cc;
            cc.h = __float2bfloat16(fmaxf(a, 0.f));
            actl[f] = cc.u;
        }
    }
    __syncthreads();

    for (int i = tid; i < D_SAE; i += 256) {
        unsigned c = actl[i];
        if (c && c < 0x8000u) atomicAdd(&hist1[c >> 7], 1u);
    }
    __syncthreads();
    if (tid < 64) {
        int l = tid;
        unsigned c0 = hist1[4 * l], c1 = hist1[4 * l + 1],
                 c2 = hist1[4 * l + 2], c3 = hist1[4 * l + 3];
        unsigned S = c0 + c1 + c2 + c3;
#pragma unroll
        for (int o = 1; o < 64; o <<= 1) {
            unsigned t = __shfl_down(S, o);
            if (l + o < 64) S += t;
        }
        unsigned above = __shfl_down(S, 1);
        if (l == 63) above = 0;
        if (S >= NCF && above < NCF) {
            int b1; unsigned ab;
            if (above + c3 >= NCF)                { b1 = 4 * l + 3; ab = above; }
            else if (above + c3 + c2 >= NCF)      { b1 = 4 * l + 2; ab = above + c3; }
            else if (above + c3 + c2 + c1 >= NCF) { b1 = 4 * l + 1; ab = above + c3 + c2; }
            else                                  { b1 = 4 * l;     ab = above + c3 + c2 + c1; }
            s_b1 = b1; s_above = ab;
        }
    }
    __syncthreads();
    int b1 = s_b1;
    if (b1 >= 0) {
        for (int i = tid; i < D_SAE; i += 256) {
            unsigned c = actl[i];
            if (c && c < 0x8000u && (int)(c >> 7) == b1) atomicAdd(&hist2[c & 127u], 1u);
        }
        __syncthreads();
        if (tid < 64) {
            int l = tid;
            unsigned above0 = s_above;
            unsigned c0 = hist2[2 * l], c1 = hist2[2 * l + 1];
            unsigned S = c0 + c1;
#pragma unroll
            for (int o = 1; o < 64; o <<= 1) {
                unsigned t = __shfl_down(S, o);
                if (l + o < 64) S += t;
            }
            unsigned ab2 = __shfl_down(S, 1);
            if (l == 63) ab2 = 0;
            if (above0 + S >= NCF && above0 + ab2 < NCF) {
                if (above0 + ab2 + c1 >= NCF) s_code = (b1 << 7) | (2 * l + 1);
                else                          s_code = (b1 << 7) | (2 * l);
            }
        }
        __syncthreads();
    }
    int code = s_code;

    for (int i = tid; i < D_SAE; i += 256) {
        unsigned c = actl[i];
        if (c < 0x8000u && (int)c >= code) {
            int slot = atomicAdd(&s_cnt, 1);
            if (slot < CFB) cand[slot] = i;
        }
    }
    __syncthreads();
    int C = s_cnt < CFB ? s_cnt : CFB;

    for (int base = 0; base < C; base += 64) {
        int ai = base + (tid >> 2), sb = tid & 3;
        if (ai < C) {
            const float* wr = wt + (size_t)cand[ai] * D_VIT;
            double a = 0.0;
            for (int k = sb * 4; k < D_VIT; k += 16) {
                float4 wv = *reinterpret_cast<const float4*>(wr + k);
                float4 xv = *reinterpret_cast<const float4*>(xs + k);
                a += (double)wv.x * xv.x + (double)wv.y * xv.y
                   + (double)wv.z * xv.z + (double)wv.w * xv.w;
            }
            a += __shfl_xor(a, 1); a += __shfl_xor(a, 2);
            if (sb == 0) cval[ai] = a > 0.0 ? a : 0.0;
        }
    }
    __syncthreads();

    for (int c = tid; c < C; c += 256) {
        double mv = cval[c]; int mi = cand[c]; int rk = 0;
        for (int j = 0; j < C; ++j) {
            double vj = cval[j]; int ij = cand[j];
            rk += (vj > mv) || (vj == mv && ij < mi);
        }
        if (rk < TOPK) { sval[rk] = (float)mv; sidx[rk] = mi; }
    }
    __syncthreads();

    if (tid < 192) {
        int d0 = tid * 4;
        float4 o = *reinterpret_cast<const float4*>(bdec + d0);
#pragma unroll
        for (int j = 0; j < TOPK; ++j) {
            float s = sval[j];
            uint2 u = *reinterpret_cast<const uint2*>(wdecb + (size_t)sidx[j] * D_VIT + d0);
            o.x = fmaf(s, __uint_as_float(u.x << 16), o.x);
            o.y = fmaf(s, __uint_as_float(u.x & 0xffff0000u), o.y);
            o.z = fmaf(s, __uint_as_float(u.y << 16), o.z);
            o.w = fmaf(s, __uint_as_float(u.y & 0xffff0000u), o.w);
        }
        *reinterpret_cast<float4*>(out + (size_t)row * D_VIT + d0) = o;
    }
}

extern "C" void kernel_launch(void* const* d_in, const int* in_sizes, int n_in,
                              void* d_out, int out_size, void* d_ws, size_t ws_size,
                              hipStream_t stream) {
    const float* x    = (const float*)d_in[0];
    const float* wenc = (const float*)d_in[1];
    const float* wdec = (const float*)d_in[2];
    const float* bdec = (const float*)d_in[3];
    float* out = (float*)d_out;
    int M = in_sizes[0] / D_VIT;

    size_t wt_b    = (size_t)D_SAE * D_VIT * sizeof(float);
    size_t wtb_b   = (size_t)D_SAE * D_VIT * sizeof(__hip_bfloat16);
    size_t xb_b    = (size_t)M * D_VIT * sizeof(__hip_bfloat16);
    size_t wdecb_b = (size_t)D_SAE * D_VIT * sizeof(__hip_bfloat16);
    size_t cnt_b   = (size_t)M * sizeof(int);
    size_t flag_b  = (size_t)M * sizeof(int);

    char* p = (char*)d_ws;
    float* wt             = (float*)p;              p += wt_b;
    __hip_bfloat16* wtb   = (__hip_bfloat16*)p;     p += wtb_b;
    __hip_bfloat16* xb    = (__hip_bfloat16*)p;     p += xb_b;
    __hip_bfloat16* wdecb = (__hip_bfloat16*)p;     p += wdecb_b;
    int* cnt              = (int*)p;                p += cnt_b;
    int* fflag            = (int*)p;                p += flag_b;
    int* candb            = (int*)p;

    hipLaunchKernelGGL(k_prep_w, dim3(NTR_BLK + NCW_BLK), dim3(256), 0, stream,
                       wenc, wt, wtb, wdec, wdecb);
    {
        long long n = (long long)M * D_VIT;
        int nxblk = (int)((n / 8 + 255) / 256);
        int nzblk = (M + 255) / 256;
        hipLaunchKernelGGL(k_prep_x, dim3(nxblk + nzblk), dim3(256), 0, stream,
                           x, bdec, xb, cnt, fflag, n, nxblk, M);
    }
    {
        dim3 ge(D_SAE / GBN, (M + GBM - 1) / GBM), be(256);
        hipLaunchKernelGGL(k_enc8, ge, be, 0, stream, xb, wtb, cnt, candb, M);
    }
    hipLaunchKernelGGL(k_select, dim3(M), dim3(256), 0, stream,
                       cnt, candb, x, bdec, wt, wdecb, out, fflag);
    hipLaunchKernelGGL(k_fallback, dim3(M), dim3(256), 0, stream,
                       fflag, x, bdec, wt, wdecb, out);
}

// Round 21
// 528.810 us; speedup vs baseline: 1.0742x; 1.0742x over previous
//
#include <hip/hip_runtime.h>
#include <hip/hip_bf16.h>
#include <stdint.h>

#define D_VIT 768
#define D_SAE 12288
#define TOPK 32
#define NC 32           // fast-path quorum: >=32 codes >= CQ(3.25)
#define CMAX 384        // candidate slots per row
#define THETA 3.1f      // encoder emission threshold (mfma-f32 domain)
#define SLOTS 24        // LDS staging slots per (row, block-col); overflow->fallback
#define NCF 48          // fallback superset size
#define CFB 512

typedef __attribute__((ext_vector_type(8))) short bf8_t;   // 8 bf16 (4 VGPRs)
typedef __attribute__((ext_vector_type(4))) float f4_t;    // 4 f32 acc
typedef __attribute__((ext_vector_type(4))) float f4v;
typedef const __attribute__((address_space(1))) void* gas_t;
typedef __attribute__((address_space(3))) void* las_t;

#define NTR_BLK 9216    // (D_SAE/32)*(D_VIT/32) transpose blocks
#define NCW_BLK 4608    // D_SAE*D_VIT/8/256 cvt_w blocks

// ---- fused: W_enc transpose (wt f32 + wtb bf16)  ||  wdecb = bf16(wdec) -----
__global__ __launch_bounds__(256) void k_prep_w(
    const float* __restrict__ wenc, float* __restrict__ wt,
    __hip_bfloat16* __restrict__ wtb, const float* __restrict__ wdec,
    __hip_bfloat16* __restrict__ wdecb) {
    int bid = blockIdx.x, tid = threadIdx.x;
    if (bid < NTR_BLK) {
        __shared__ float t[32][33];
        int f0 = (bid % 384) * 32, k0 = (bid / 384) * 32;
        int tx = tid & 31, ty = tid >> 5;
#pragma unroll
        for (int j = 0; j < 32; j += 8)
            t[ty + j][tx] = wenc[(size_t)(k0 + ty + j) * D_SAE + f0 + tx];
        __syncthreads();
#pragma unroll
        for (int j = 0; j < 32; j += 8) {
            float v = t[tx][ty + j];
            wt[(size_t)(f0 + ty + j) * D_VIT + k0 + tx] = v;
            wtb[(size_t)(f0 + ty + j) * D_VIT + k0 + tx] = __float2bfloat16(v);
        }
    } else {
        long long i = ((long long)(bid - NTR_BLK) * 256 + tid) * 8;
        float4 a = *reinterpret_cast<const float4*>(wdec + i);
        float4 b = *reinterpret_cast<const float4*>(wdec + i + 4);
        union { __hip_bfloat16 h[8]; uint4 v; } o;
        o.h[0] = __float2bfloat16(a.x); o.h[1] = __float2bfloat16(a.y);
        o.h[2] = __float2bfloat16(a.z); o.h[3] = __float2bfloat16(a.w);
        o.h[4] = __float2bfloat16(b.x); o.h[5] = __float2bfloat16(b.y);
        o.h[6] = __float2bfloat16(b.z); o.h[7] = __float2bfloat16(b.w);
        *reinterpret_cast<uint4*>(wdecb + i) = o.v;
    }
}

// ---- fused: xb = bf16(x - b_dec)  ||  zero cnt/fflag ------------------------
__global__ __launch_bounds__(256) void k_prep_x(
    const float* __restrict__ x, const float* __restrict__ bdec,
    __hip_bfloat16* __restrict__ xb, int* __restrict__ cnt,
    int* __restrict__ fflag, long long n, int nxblk, int M) {
    int bid = blockIdx.x, tid = threadIdx.x;
    if (bid < nxblk) {
        long long i = ((long long)bid * 256 + tid) * 8;
        if (i >= n) return;
        float4 a = *reinterpret_cast<const float4*>(x + i);
        float4 b = *reinterpret_cast<const float4*>(x + i + 4);
        int kk = (int)(i % D_VIT);
        float4 c = *reinterpret_cast<const float4*>(bdec + kk);
        float4 d = *reinterpret_cast<const float4*>(bdec + kk + 4);
        union { __hip_bfloat16 h[8]; uint4 v; } o;
        o.h[0] = __float2bfloat16(a.x - c.x); o.h[1] = __float2bfloat16(a.y - c.y);
        o.h[2] = __float2bfloat16(a.z - c.z); o.h[3] = __float2bfloat16(a.w - c.w);
        o.h[4] = __float2bfloat16(b.x - d.x); o.h[5] = __float2bfloat16(b.y - d.y);
        o.h[6] = __float2bfloat16(b.z - d.z); o.h[7] = __float2bfloat16(b.w - d.w);
        *reinterpret_cast<uint4*>(xb + i) = o.v;
    } else {
        int i = (bid - nxblk) * 256 + tid;
        if (i < M) { cnt[i] = 0; fflag[i] = 0; }
    }
}

// ------- 256x256x64 8-wave dbuf MFMA encoder -> LDS-staged candidate emit ----
#define GBM 256
#define GBN 256
#define GBK 64
#define NKT (D_VIT / GBK)   // 12

__global__ __launch_bounds__(512, 2) void k_enc8(
    const __hip_bfloat16* __restrict__ xb, const __hip_bfloat16* __restrict__ wtb,
    int* __restrict__ cnt, int* __restrict__ candb, int mrows) {
    __shared__ __hip_bfloat16 lds[2][2][GBM * GBK];   // 128 KiB (reused by epilogue)
    int tid = threadIdx.x;
    int lane = tid & 63, w = tid >> 6;
    int wm = w >> 2, wn = w & 3;
    int tile_m = blockIdx.y * GBM, tile_n = blockIdx.x * GBN;
    int lrow = lane & 15, lk = lane >> 4;
    int G0 = w * 64 + lane;

    f4_t acc[2][4][2][2] = {};

    auto STAGE = [&](int kt, int h, int b) {
#pragma unroll
        for (int j = 0; j < 2; ++j) {
            int G = G0 + j * 512;
            int r = G >> 3, s = G & 7;
            int gg = s ^ (r & 7);
            int half = h >> 1;
            if ((h & 1) == 0) {
                int ar = tile_m + half * 128 + r;
                if (ar >= mrows) ar = mrows - 1;
                const __hip_bfloat16* src = xb + (size_t)ar * D_VIT + kt * GBK + gg * 8;
                __builtin_amdgcn_global_load_lds((gas_t)src,
                    (las_t)(&lds[b][0][half * 8192 + (w * 64 + j * 512) * 8]), 16, 0, 0);
            } else {
                int br = tile_n + half * 128 + r;
                const __hip_bfloat16* src = wtb + (size_t)br * D_VIT + kt * GBK + gg * 8;
                __builtin_amdgcn_global_load_lds((gas_t)src,
                    (las_t)(&lds[b][1][half * 8192 + (w * 64 + j * 512) * 8]), 16, 0, 0);
            }
        }
    };

#define PHASE(MQ, NQ, BUF) do {                                                \
        const __hip_bfloat16* Ab = &lds[BUF][0][0];                            \
        const __hip_bfloat16* Bb = &lds[BUF][1][0];                            \
        bf8_t af[4][2], bv[2][2];                                              \
        _Pragma("unroll")                                                      \
        for (int f = 0; f < 4; ++f) {                                          \
            int ra = wm * 128 + (MQ) * 64 + f * 16 + lrow;                     \
            _Pragma("unroll")                                                  \
            for (int h = 0; h < 2; ++h) {                                      \
                int sl = (lk + 4 * h) ^ (ra & 7);                              \
                af[f][h] = *reinterpret_cast<const bf8_t*>(Ab + ra * GBK + sl * 8); \
            }                                                                  \
        }                                                                      \
        _Pragma("unroll")                                                      \
        for (int g = 0; g < 2; ++g) {                                          \
            int rb = wn * 64 + (NQ) * 32 + g * 16 + lrow;                      \
            _Pragma("unroll")                                                  \
            for (int h = 0; h < 2; ++h) {                                      \
                int sl = (lk + 4 * h) ^ (rb & 7);                              \
                bv[g][h] = *reinterpret_cast<const bf8_t*>(Bb + rb * GBK + sl * 8); \
            }                                                                  \
        }                                                                      \
        __builtin_amdgcn_s_setprio(1);                                         \
        _Pragma("unroll")                                                      \
        for (int h = 0; h < 2; ++h)                                            \
            _Pragma("unroll")                                                  \
            for (int f = 0; f < 4; ++f)                                        \
                _Pragma("unroll")                                              \
                for (int g = 0; g < 2; ++g)                                    \
                    acc[MQ][f][NQ][g] = __builtin_amdgcn_mfma_f32_16x16x32_bf16( \
                        bv[g][h], af[f][h], acc[MQ][f][NQ][g], 0, 0, 0);       \
        __builtin_amdgcn_s_setprio(0);                                         \
    } while (0)

#pragma unroll
    for (int h = 0; h < 4; ++h) STAGE(0, h, 0);

    int cur = 0;
#pragma unroll 1
    for (int t = 0; t < NKT; ++t) {
        int nb = cur ^ 1;
        bool pf = (t + 1 < NKT);
        if (pf) STAGE(t + 1, 0, nb);
        if (pf) asm volatile("s_waitcnt vmcnt(2)" ::: "memory");
        else    asm volatile("s_waitcnt vmcnt(0)" ::: "memory");
        __builtin_amdgcn_s_barrier();
        asm volatile("" ::: "memory");
        __builtin_amdgcn_sched_barrier(0);
        PHASE(0, 0, cur);
        if (pf) STAGE(t + 1, 1, nb);
        PHASE(1, 0, cur);
        if (pf) STAGE(t + 1, 2, nb);
        PHASE(0, 1, cur);
        if (pf) STAGE(t + 1, 3, nb);
        PHASE(1, 1, cur);
        asm volatile("" ::: "memory");
        __builtin_amdgcn_s_barrier();
        asm volatile("" ::: "memory");
        cur = nb;
    }
#undef PHASE

    // ---- epilogue: LDS-staged candidate emission (no global atomics in loop)
    __syncthreads();
    int* scnt  = reinterpret_cast<int*>(&lds[0][0][0]);   // [256]
    int* scand = scnt + 256;                              // [256][SLOTS]
    for (int r = tid; r < 256; r += 512) scnt[r] = 0;
    __syncthreads();

#pragma unroll
    for (int mq = 0; mq < 2; ++mq)
#pragma unroll
        for (int f = 0; f < 4; ++f) {
            int lr = wm * 128 + mq * 64 + f * 16 + lrow;
            int xr = tile_m + lr;
            if (xr < mrows) {
#pragma unroll
                for (int nq = 0; nq < 2; ++nq)
#pragma unroll
                    for (int g = 0; g < 2; ++g) {
                        int fb = tile_n + wn * 64 + nq * 32 + g * 16 + lk * 4;
#pragma unroll
                        for (int q = 0; q < 4; ++q) {
                            float r = acc[mq][f][nq][g][q];
                            if (r >= THETA) {
                                int slot = atomicAdd(&scnt[lr], 1);   // LDS atomic
                                if (slot < SLOTS) {
                                    union { __hip_bfloat16 h; unsigned short u; } cc;
                                    cc.h = __float2bfloat16(r);
                                    scand[lr * SLOTS + slot] =
                                        (int)(((unsigned)cc.u << 16) | (unsigned)(fb + q));
                                }
                            }
                        }
                    }
            }
        }
    __syncthreads();

    // flush: one global atomic per (row, block) — 256 in parallel
    if (tid < 256) {
        int xr = tile_m + tid;
        if (xr < mrows) {
            int c = scnt[tid];
            if (c > SLOTS) {
                atomicAdd(&cnt[xr], CMAX + 1);     // poison -> fallback (sum-deterministic)
            } else if (c > 0) {
                int base = atomicAdd(&cnt[xr], c);
                for (int i = 0; i < c; ++i) {
                    int g = base + i;
                    if (g < CMAX) candb[(size_t)xr * CMAX + g] = scand[tid * SLOTS + i];
                }
            }
        }
    }
}

// -------- per-row select: hist-vb -> band f64 rerank -> compact route --------
__global__ __launch_bounds__(256) void k_select(
    const int* __restrict__ cnt, const int* __restrict__ candb,
    const float* __restrict__ x, const float* __restrict__ bdec,
    const float* __restrict__ wt, const __hip_bfloat16* __restrict__ wdecb,
    float* __restrict__ out, int* __restrict__ fflag) {
    int row = blockIdx.x, tid = threadIdx.x;

    __shared__ float xs[D_VIT];
    __shared__ int cand[CMAX];
    __shared__ unsigned int hist[256];
    __shared__ float cvfin[CMAX];
    __shared__ float cexact[CMAX];
    __shared__ unsigned char cflag[CMAX];
    __shared__ short alist[CMAX];
    __shared__ short clist[TOPK];
    __shared__ float sval[TOPK];
    __shared__ int sidx[TOPK];
    __shared__ int s_nq, s_na, s_nd, s_nc, s_vbc;

    hist[tid] = 0;
    for (int c = tid; c < CMAX; c += 256) cflag[c] = 0;
    if (tid < TOPK) { sval[tid] = 0.f; sidx[tid] = 0; }
    if (tid == 0) { s_nq = 0; s_na = 0; s_nd = 0; s_nc = 0; s_vbc = 255; }
    if (tid < 192) {
        const float* xp = x + (size_t)row * D_VIT + tid * 4;
        float4 xv = *reinterpret_cast<const float4*>(xp);
        float4 bv = *reinterpret_cast<const float4*>(bdec + tid * 4);
        xs[tid * 4 + 0] = xv.x - bv.x; xs[tid * 4 + 1] = xv.y - bv.y;
        xs[tid * 4 + 2] = xv.z - bv.z; xs[tid * 4 + 3] = xv.w - bv.w;
    }
    int C0 = cnt[row];
    int C = C0 < CMAX ? C0 : CMAX;

    // load candidates + quorum + code histogram in one pass.
    unsigned CQ;
    { union { __hip_bfloat16 h; unsigned short u; } t2; t2.h = __float2bfloat16(3.25f); CQ = t2.u; }
    int nql = 0;
    for (int c = tid; c < C; c += 256) {
        int pk = candb[(size_t)row * CMAX + c];
        cand[c] = pk;
        unsigned code = (unsigned)pk >> 16;
        if (code >= CQ) nql++;
        int bin = (int)code - 0x4040;
        if (bin < 0) bin = 0; if (bin > 255) bin = 255;
        atomicAdd(&hist[bin], 1u);
    }
    if (nql) atomicAdd(&s_nq, nql);
    __syncthreads();

    // quorum: >=NC codes >= bf16(3.25). Exclusion proof: 32nd exact >=
    // 3.25-0.016-0.019 = 3.215 > excluded exact < 3.1+0.035 = 3.135.
    if (C0 > CMAX || s_nq < NC) {
        if (tid == 0) fflag[row] = 1;
        return;
    }

    // vb = 32nd-largest CODE via suffix scan over the 256-bin histogram (exact)
    if (tid < 64) {
        int l = tid;
        unsigned c0 = hist[4 * l], c1 = hist[4 * l + 1],
                 c2 = hist[4 * l + 2], c3 = hist[4 * l + 3];
        unsigned S = c0 + c1 + c2 + c3;
#pragma unroll
        for (int o = 1; o < 64; o <<= 1) {
            unsigned t = __shfl_down(S, o);
            if (l + o < 64) S += t;
        }
        unsigned above = __shfl_down(S, 1);
        if (l == 63) above = 0;
        if (S >= TOPK && above < TOPK) {
            unsigned run = above;
            int bs = 4 * l;
            if (run + c3 >= TOPK)                 bs = 4 * l + 3;
            else if (run + c3 + c2 >= TOPK)       bs = 4 * l + 2;
            else if (run + c3 + c2 + c1 >= TOPK)  bs = 4 * l + 1;
            s_vbc = bs;
        }
    }
    __syncthreads();
    int vbc = s_vbc;
    if (vbc >= 255) {                      // degenerate tail -> exact fallback
        if (tid == 0) fflag[row] = 1;
        return;
    }
    float vb = __uint_as_float((unsigned)(0x4040 + vbc) << 16);

    // partition: definite-in / ambiguous band / excluded
    {
        float band = 0.025f + 0.018f * vb;
        for (int c = tid; c < C; c += 256) {
            float v = __uint_as_float(((unsigned)cand[c] >> 16) << 16);
            if (v > vb + band) { cflag[c] = 2; cvfin[c] = v; atomicAdd(&s_nd, 1); }
            else if (v >= vb - band) { int a = atomicAdd(&s_na, 1); alist[a] = (short)c; cflag[c] = 1; }
        }
    }
    __syncthreads();
    int na = s_na, nd = s_nd;

    // f64 rerank of band: 16 threads/cand -> 16 cands/pass
    for (int base = 0; base < na; base += 16) {
        int ai = base + (tid >> 4), sub = tid & 15;
        if (ai < na) {
            int c = alist[ai];
            int f = (int)(((unsigned)cand[c]) & 0xffffu);
            const float* wr = wt + (size_t)f * D_VIT;
            double acc = 0.0;
#pragma unroll
            for (int i = 0; i < 12; ++i) {
                int k = sub * 4 + i * 64;
                float4 wv = *reinterpret_cast<const float4*>(wr + k);
                float4 xv = *reinterpret_cast<const float4*>(xs + k);
                acc += (double)wv.x * xv.x + (double)wv.y * xv.y
                     + (double)wv.z * xv.z + (double)wv.w * xv.w;
            }
            acc += __shfl_xor(acc, 1);  acc += __shfl_xor(acc, 2);
            acc += __shfl_xor(acc, 4);  acc += __shfl_xor(acc, 8);
            if (sub == 0) cexact[c] = (float)(acc > 0.0 ? acc : 0.0);
        }
    }
    __syncthreads();

    // choose top (32-nd) of the band by exact value (na x na, small)
    {
        int kq = TOPK - nd;
        for (int a = tid; a < na; a += 256) {
            int c = alist[a];
            float ex = cexact[c]; int mi = (int)(((unsigned)cand[c]) & 0xffffu);
            int rA = 0;
            for (int j = 0; j < na; ++j) {
                int cj = alist[j];
                float ej = cexact[cj]; int ij = (int)(((unsigned)cand[cj]) & 0xffffu);
                rA += (ej > ex) || (ej == ex && ij < mi);
            }
            if (rA < kq) { cflag[c] = 3; cvfin[c] = ex; }
        }
    }
    __syncthreads();

    // compact chosen (exactly 32) then content-rank 32 over 32
    for (int c = tid; c < C; c += 256) if (cflag[c] >= 2) {
        int a = atomicAdd(&s_nc, 1);
        if (a < TOPK) clist[a] = (short)c;
    }
    __syncthreads();
    if (tid < TOPK && tid < s_nc) {
        int c = clist[tid];
        float mv = cvfin[c]; int mi = (int)(((unsigned)cand[c]) & 0xffffu);
        int rk = 0;
        for (int j = 0; j < TOPK && j < s_nc; ++j) {
            int cj = clist[j];
            float vj = cvfin[cj]; int ij = (int)(((unsigned)cand[cj]) & 0xffffu);
            rk += (vj > mv) || (vj == mv && ij < mi);
        }
        if (rk < TOPK) { sval[rk] = mv; sidx[rk] = mi; }
    }
    __syncthreads();

    // decode: 8-wide explicit prefetch (4 serial round-trips instead of 32)
    if (tid < 192) {
        int d0 = tid * 4;
        float4 o = *reinterpret_cast<const float4*>(bdec + d0);
#pragma unroll
        for (int g = 0; g < 4; ++g) {
            uint2 u[8];
#pragma unroll
            for (int j = 0; j < 8; ++j)
                u[j] = *reinterpret_cast<const uint2*>(
                    wdecb + (size_t)sidx[g * 8 + j] * D_VIT + d0);
#pragma unroll
            for (int j = 0; j < 8; ++j) {
                float s = sval[g * 8 + j];
                o.x = fmaf(s, __uint_as_float(u[j].x << 16), o.x);
                o.y = fmaf(s, __uint_as_float(u[j].x & 0xffff0000u), o.y);
                o.z = fmaf(s, __uint_as_float(u[j].y << 16), o.z);
                o.w = fmaf(s, __uint_as_float(u[j].y & 0xffff0000u), o.w);
            }
        }
        f4v ov; ov.x = o.x; ov.y = o.y; ov.z = o.z; ov.w = o.w;
        __builtin_nontemporal_store(ov,
            reinterpret_cast<f4v*>(out + (size_t)row * D_VIT + d0));
    }
}

// -------- fallback: coalesced full f32 recompute, any-distribution exact -----
__global__ __launch_bounds__(256) void k_fallback(
    const int* __restrict__ fflag, const float* __restrict__ x,
    const float* __restrict__ bdec, const float* __restrict__ wt,
    const __hip_bfloat16* __restrict__ wdecb, float* __restrict__ out) {
    int row = blockIdx.x;
    if (fflag[row] == 0) return;
    int tid = threadIdx.x;

    __shared__ float xs[D_VIT];
    __shared__ unsigned short actl[D_SAE];
    __shared__ unsigned int hist1[256];
    __shared__ unsigned int hist2[128];
    __shared__ int cand[CFB];
    __shared__ double cval[CFB];
    __shared__ float sval[TOPK];
    __shared__ int sidx[TOPK];
    __shared__ int s_cnt, s_b1, s_code;
    __shared__ unsigned int s_above;

    hist1[tid] = 0;
    if (tid < 128) hist2[tid] = 0;
    if (tid < TOPK) { sval[tid] = 0.f; sidx[tid] = 0; }
    if (tid == 0) { s_cnt = 0; s_b1 = -1; s_code = 1; s_above = 0; }
    if (tid < 192) {
        float4 xv = *reinterpret_cast<const float4*>(x + (size_t)row * D_VIT + tid * 4);
        float4 bv = *reinterpret_cast<const float4*>(bdec + tid * 4);
        xs[tid * 4 + 0] = xv.x - bv.x; xs[tid * 4 + 1] = xv.y - bv.y;
        xs[tid * 4 + 2] = xv.z - bv.z; xs[tid * 4 + 3] = xv.w - bv.w;
    }
    __syncthreads();

    int fg = tid >> 2, sub = tid & 3;
    for (int pass = 0; pass < D_SAE / 64; ++pass) {
        int f = pass * 64 + fg;
        const float* wr = wt + (size_t)f * D_VIT;
        float a = 0.f;
        for (int j = 0; j < 48; ++j) {
            int k = sub * 4 + j * 16;
            float4 wv = *reinterpret_cast<const float4*>(wr + k);
            float4 xv = *reinterpret_cast<const float4*>(xs + k);
            a = fmaf(wv.x, xv.x, a); a = fmaf(wv.y, xv.y, a);
            a = fmaf(wv.z, xv.z, a); a = fmaf(wv.w, xv.w, a);
        }
        a += __shfl_xor(a, 1); a += __shfl_xor(a, 2);
        if (sub == 0) {
            union { __hip_bfloat16 h; unsigned short u; } cc;
            cc.h = __float2bfloat16(fmaxf(a, 0.f));
            actl[f] = cc.u;
        }
    }
    __syncthreads();

    for (int i = tid; i < D_SAE; i += 256) {
        unsigned c = actl[i];
        if (c && c < 0x8000u) atomicAdd(&hist1[c >> 7], 1u);
    }
    __syncthreads();
    if (tid < 64) {
        int l = tid;
        unsigned c0 = hist1[4 * l], c1 = hist1[4 * l + 1],
                 c2 = hist1[4 * l + 2], c3 = hist1[4 * l + 3];
        unsigned S = c0 + c1 + c2 + c3;
#pragma unroll
        for (int o = 1; o < 64; o <<= 1) {
            unsigned t = __shfl_down(S, o);
            if (l + o < 64) S += t;
        }
        unsigned above = __shfl_down(S, 1);
        if (l == 63) above = 0;
        if (S >= NCF && above < NCF) {
            int b1; unsigned ab;
            if (above + c3 >= NCF)                { b1 = 4 * l + 3; ab = above; }
            else if (above + c3 + c2 >= NCF)      { b1 = 4 * l + 2; ab = above + c3; }
            else if (above + c3 + c2 + c1 >= NCF) { b1 = 4 * l + 1; ab = above + c3 + c2; }
            else                                  { b1 = 4 * l;     ab = above + c3 + c2 + c1; }
            s_b1 = b1; s_above = ab;
        }
    }
    __syncthreads();
    int b1 = s_b1;
    if (b1 >= 0) {
        for (int i = tid; i < D_SAE; i += 256) {
            unsigned c = actl[i];
            if (c && c < 0x8000u && (int)(c >> 7) == b1) atomicAdd(&hist2[c & 127u], 1u);
        }
        __syncthreads();
        if (tid < 64) {
            int l = tid;
            unsigned above0 = s_above;
            unsigned c0 = hist2[2 * l], c1 = hist2[2 * l + 1];
            unsigned S = c0 + c1;
#pragma unroll
            for (int o = 1; o < 64; o <<= 1) {
                unsigned t = __shfl_down(S, o);
                if (l + o < 64) S += t;
            }
            unsigned ab2 = __shfl_down(S, 1);
            if (l == 63) ab2 = 0;
            if (above0 + S >= NCF && above0 + ab2 < NCF) {
                if (above0 + ab2 + c1 >= NCF) s_code = (b1 << 7) | (2 * l + 1);
                else                          s_code = (b1 << 7) | (2 * l);
            }
        }
        __syncthreads();
    }
    int code = s_code;

    for (int i = tid; i < D_SAE; i += 256) {
        unsigned c = actl[i];
        if (c < 0x8000u && (int)c >= code) {
            int slot = atomicAdd(&s_cnt, 1);
            if (slot < CFB) cand[slot] = i;
        }
    }
    __syncthreads();
    int C = s_cnt < CFB ? s_cnt : CFB;

    for (int base = 0; base < C; base += 64) {
        int ai = base + (tid >> 2), sb = tid & 3;
        if (ai < C) {
            const float* wr = wt + (size_t)cand[ai] * D_VIT;
            double a = 0.0;
            for (int k = sb * 4; k < D_VIT; k += 16) {
                float4 wv = *reinterpret_cast<const float4*>(wr + k);
                float4 xv = *reinterpret_cast<const float4*>(xs + k);
                a += (double)wv.x * xv.x + (double)wv.y * xv.y
                   + (double)wv.z * xv.z + (double)wv.w * xv.w;
            }
            a += __shfl_xor(a, 1); a += __shfl_xor(a, 2);
            if (sb == 0) cval[ai] = a > 0.0 ? a : 0.0;
        }
    }
    __syncthreads();

    for (int c = tid; c < C; c += 256) {
        double mv = cval[c]; int mi = cand[c]; int rk = 0;
        for (int j = 0; j < C; ++j) {
            double vj = cval[j]; int ij = cand[j];
            rk += (vj > mv) || (vj == mv && ij < mi);
        }
        if (rk < TOPK) { sval[rk] = (float)mv; sidx[rk] = mi; }
    }
    __syncthreads();

    if (tid < 192) {
        int d0 = tid * 4;
        float4 o = *reinterpret_cast<const float4*>(bdec + d0);
#pragma unroll
        for (int j = 0; j < TOPK; ++j) {
            float s = sval[j];
            uint2 u = *reinterpret_cast<const uint2*>(wdecb + (size_t)sidx[j] * D_VIT + d0);
            o.x = fmaf(s, __uint_as_float(u.x << 16), o.x);
            o.y = fmaf(s, __uint_as_float(u.x & 0xffff0000u), o.y);
            o.z = fmaf(s, __uint_as_float(u.y << 16), o.z);
            o.w = fmaf(s, __uint_as_float(u.y & 0xffff0000u), o.w);
        }
        *reinterpret_cast<float4*>(out + (size_t)row * D_VIT + d0) = o;
    }
}

extern "C" void kernel_launch(void* const* d_in, const int* in_sizes, int n_in,
                              void* d_out, int out_size, void* d_ws, size_t ws_size,
                              hipStream_t stream) {
    const float* x    = (const float*)d_in[0];
    const float* wenc = (const float*)d_in[1];
    const float* wdec = (const float*)d_in[2];
    const float* bdec = (const float*)d_in[3];
    float* out = (float*)d_out;
    int M = in_sizes[0] / D_VIT;

    size_t wt_b    = (size_t)D_SAE * D_VIT * sizeof(float);
    size_t wtb_b   = (size_t)D_SAE * D_VIT * sizeof(__hip_bfloat16);
    size_t xb_b    = (size_t)M * D_VIT * sizeof(__hip_bfloat16);
    size_t wdecb_b = (size_t)D_SAE * D_VIT * sizeof(__hip_bfloat16);
    size_t cnt_b   = (size_t)M * sizeof(int);
    size_t flag_b  = (size_t)M * sizeof(int);

    char* p = (char*)d_ws;
    float* wt             = (float*)p;              p += wt_b;
    __hip_bfloat16* wtb   = (__hip_bfloat16*)p;     p += wtb_b;
    __hip_bfloat16* xb    = (__hip_bfloat16*)p;     p += xb_b;
    __hip_bfloat16* wdecb = (__hip_bfloat16*)p;     p += wdecb_b;
    int* cnt              = (int*)p;                p += cnt_b;
    int* fflag            = (int*)p;                p += flag_b;
    int* candb            = (int*)p;

    hipLaunchKernelGGL(k_prep_w, dim3(NTR_BLK + NCW_BLK), dim3(256), 0, stream,
                       wenc, wt, wtb, wdec, wdecb);
    {
        long long n = (long long)M * D_VIT;
        int nxblk = (int)((n / 8 + 255) / 256);
        int nzblk = (M + 255) / 256;
        hipLaunchKernelGGL(k_prep_x, dim3(nxblk + nzblk), dim3(256), 0, stream,
                           x, bdec, xb, cnt, fflag, n, nxblk, M);
    }
    {
        dim3 ge(D_SAE / GBN, (M + GBM - 1) / GBM), be(512);
        hipLaunchKernelGGL(k_enc8, ge, be, 0, stream, xb, wtb, cnt, candb, M);
    }
    hipLaunchKernelGGL(k_select, dim3(M), dim3(256), 0, stream,
                       cnt, candb, x, bdec, wt, wdecb, out, fflag);
    hipLaunchKernelGGL(k_fallback, dim3(M), dim3(256), 0, stream,
                       fflag, x, bdec, wt, wdecb, out);
}